// Round 12
// baseline (165.911 us; speedup 1.0000x reference)
//
#include <hip/hip_runtime.h>
#include <math.h>

// ---------------------------------------------------------------------------
// TitansMemoryModule fused update, MI355X (gfx950) — round 12
//   K1: pure f32->bf16 convert of K,W + grad/scal zero (r10 proven)
//   K2: REVERTED to proven drain-barrier GEMM (77us, passed r2/8/9/10)
//   K3: grad = diff^T @ k, r9-proven lgkmcnt pipeline; PARAMETER change:
//       split-K 64 chunks of 512 rows (1024 blocks = 4/CU TLP, 16 steps)
//   cR/c1b/cF: r10 proven (dots + closed-form norms + single final pass)
// Output (flat f32): retrieved[16777216], loss, new_weight[262144],
//   new_momentum[262144], alpha, eta, theta
// ---------------------------------------------------------------------------

typedef __bf16 bf16x8 __attribute__((ext_vector_type(8)));
typedef float f32x4 __attribute__((ext_vector_type(4)));
typedef float float4_t __attribute__((ext_vector_type(4)));
typedef unsigned short ushort4_t __attribute__((ext_vector_type(4)));
typedef unsigned short ushort8_t __attribute__((ext_vector_type(8)));

#define OUT_LOSS   16777216
#define OUT_W      16777217
#define OUT_MOM    17039361
#define OUT_ALPHA  17301505

// ws layout (bytes)
#define OFF_GRAD   0u           // grad accum [512][512] f32 = 1 MB [K1 zeroes]
#define OFF_CKP    1048576u     // colk_part [64][512] f32 = 128 KB (K3)
#define OFF_CVP    1572864u     // colv_part [256][512] f32 (K2)
#define OFF_LOSSP  2097152u     // loss_part [1024] f32 (K2)
#define OFF_COLK   2105344u     // colk [512] f32
#define OFF_COLV   2107392u     // colv [512] f32
#define OFF_SCAL   2109440u     // scal[16]: 3=a 4=e 5=t 6=sm 7=sw 8..13=dots
#define OFF_W16    2109504u     // 512 KB bf16 W
#define OFF_K16    2633792u     // 32 MB bf16 K (row-major)
#define OFF_DIFF   36188224u    // 32 MB bf16 diff (row-major)

__device__ __forceinline__ ushort4_t cvt4(float4_t v) {
  union { __bf16 b; unsigned short u; } c0, c1, c2, c3;
  c0.b = (__bf16)v.x; c1.b = (__bf16)v.y; c2.b = (__bf16)v.z; c3.b = (__bf16)v.w;
  ushort4_t h; h.x = c0.u; h.y = c1.u; h.z = c2.u; h.w = c3.u;
  return h;
}

__device__ __forceinline__ float bf2f(unsigned short u) {
  return __uint_as_float(((unsigned int)u) << 16);
}

__device__ __forceinline__ void gload_lds16(const unsigned short* g, unsigned short* l) {
  __builtin_amdgcn_global_load_lds(
      (const __attribute__((address_space(1))) unsigned int*)g,
      (__attribute__((address_space(3))) unsigned int*)l, 16, 0, 0);
}

// ---------------------------------------------------------------------------
// K1: pure convert, high MLP. Blocks 0..1023: K; 1024..1039: W;
// 1040..1055: zero grad (+ scal on block 1040).
// ---------------------------------------------------------------------------
__global__ __launch_bounds__(256) void k1_convert(
    const float* __restrict__ Kp, const float* __restrict__ Wp,
    unsigned short* __restrict__ k16, unsigned short* __restrict__ w16,
    float* __restrict__ grad, float* __restrict__ scal)
{
  const int b = blockIdx.x;
  const int t = threadIdx.x;
  if (b < 1040) {
    const float* src = (b < 1024) ? Kp : Wp;
    unsigned short* dst = (b < 1024) ? k16 : w16;
    const size_t base = (size_t)(b < 1024 ? b : b - 1024) * 16384;
#pragma unroll
    for (int j = 0; j < 8; ++j) {
      const size_t off = base + (size_t)j * 2048 + ((size_t)t << 3);
      const float4_t v0 = *reinterpret_cast<const float4_t*>(&src[off]);
      const float4_t v1 = *reinterpret_cast<const float4_t*>(&src[off + 4]);
      const ushort4_t h0 = cvt4(v0), h1 = cvt4(v1);
      ushort8_t h;
      h[0] = h0.x; h[1] = h0.y; h[2] = h0.z; h[3] = h0.w;
      h[4] = h1.x; h[5] = h1.y; h[6] = h1.z; h[7] = h1.w;
      *reinterpret_cast<ushort8_t*>(&dst[off]) = h;
    }
  } else {
    const int base = (b - 1040) << 14;
    const float4_t z = (float4_t){0.f, 0.f, 0.f, 0.f};
#pragma unroll
    for (int j = 0; j < 16; ++j)
      *reinterpret_cast<float4_t*>(&grad[base + (j << 10) + (t << 2)]) = z;
    if (b == 1040 && t < 16) scal[t] = 0.f;
  }
}

// ---------------------------------------------------------------------------
// K2: retrieved = k16 @ w16^T.  Proven structure (77us): 128x128 tile,
// BK=64, 4 waves, single-buffer, global_load_lds(16B), linear LDS,
// XCD-grouped swizzle, fused epilogue.
// ---------------------------------------------------------------------------
__global__ __launch_bounds__(256) void k2_gemm(
    const unsigned short* __restrict__ k16, const unsigned short* __restrict__ w16,
    const float* __restrict__ Vp, float* __restrict__ outp,
    unsigned short* __restrict__ diff16,
    float* __restrict__ colv_part, float* __restrict__ loss_part)
{
  __shared__ __align__(16) unsigned short As[8192];
  __shared__ __align__(16) unsigned short Bs[8192];
  __shared__ float redc[256];
  __shared__ float redl[4];

  const int t = threadIdx.x, lane = t & 63, wv = t >> 6;
  const int tile = (blockIdx.x & 7) * 128 + (blockIdx.x >> 3);
  const int rt = tile >> 2, vt = tile & 3;
  const int row0 = rt << 7, vd0 = vt << 7;

  f32x4 acc[4][4];
#pragma unroll
  for (int m = 0; m < 4; ++m)
#pragma unroll
    for (int n = 0; n < 4; ++n)
      acc[m][n] = (f32x4){0.f, 0.f, 0.f, 0.f};

  const int srow = (wv << 3) + (lane >> 3);
  const int scol = (lane & 7) << 3;
  const unsigned short* pA = k16 + (size_t)(row0 + srow) * 512 + scol;
  const unsigned short* pB = w16 + (size_t)(vd0 + srow) * 512 + scol;
  unsigned short* lA = &As[wv << 9];
  unsigned short* lB = &Bs[wv << 9];

  const int fr = lane & 15, fq = lane >> 4;
  const int wr = (wv >> 1) << 6, wc = (wv & 1) << 6;

  for (int kk0 = 0; kk0 < 512; kk0 += 64) {
#pragma unroll
    for (int i = 0; i < 4; ++i) {
      gload_lds16(pA + (i << 14) + kk0, lA + (i << 11));
      gload_lds16(pB + (i << 14) + kk0, lB + (i << 11));
    }
    __syncthreads();
#pragma unroll
    for (int kk = 0; kk < 64; kk += 32) {
      const int co = kk + (fq << 3);
      bf16x8 af[4], bfv[4];
#pragma unroll
      for (int m = 0; m < 4; ++m)
        af[m] = *reinterpret_cast<const bf16x8*>(&As[((wr + (m << 4) + fr) << 6) + co]);
#pragma unroll
      for (int n = 0; n < 4; ++n)
        bfv[n] = *reinterpret_cast<const bf16x8*>(&Bs[((wc + (n << 4) + fr) << 6) + co]);
#pragma unroll
      for (int m = 0; m < 4; ++m)
#pragma unroll
        for (int n = 0; n < 4; ++n)
          acc[m][n] = __builtin_amdgcn_mfma_f32_16x16x32_bf16(af[m], bfv[n], acc[m][n], 0, 0, 0);
    }
    __syncthreads();
  }

  float lsum = 0.f;
  float vcs[4] = {0.f, 0.f, 0.f, 0.f};
#pragma unroll
  for (int m = 0; m < 4; ++m) {
#pragma unroll
    for (int n = 0; n < 4; ++n) {
#pragma unroll
      for (int i = 0; i < 4; ++i) {
        const int gr = row0 + wr + (m << 4) + (fq << 2) + i;
        const int gc = vd0 + wc + (n << 4) + fr;
        const size_t oi = (size_t)gr * 512 + gc;
        const float rv = acc[m][n][i];
        outp[oi] = rv;
        const float vv = Vp[oi];
        const float d = rv - vv;
        lsum += d * d;
        vcs[n] += vv;
        union { __bf16 b; unsigned short u; } cd; cd.b = (__bf16)d;
        diff16[oi] = cd.u;
      }
    }
  }
#pragma unroll
  for (int o = 32; o; o >>= 1) lsum += __shfl_xor(lsum, o);
  if (lane == 0) redl[wv] = lsum;
#pragma unroll
  for (int n = 0; n < 4; ++n) {
    vcs[n] += __shfl_xor(vcs[n], 16);
    vcs[n] += __shfl_xor(vcs[n], 32);
  }
  if (fq == 0) {
#pragma unroll
    for (int n = 0; n < 4; ++n)
      redc[(wv << 6) + (n << 4) + fr] = vcs[n];
  }
  __syncthreads();
  if (t < 128) {
    const int side = t >> 6, lc = t & 63;
    colv_part[(size_t)rt * 512 + vd0 + t] =
        redc[side * 64 + lc] + redc[(side + 2) * 64 + lc];
  }
  if (t == 0)
    loss_part[tile] = redl[0] + redl[1] + redl[2] + redl[3];
}

// ---------------------------------------------------------------------------
// K3: grad += diff^T @ k. r9-proven lgkmcnt pipeline; split-K = 64 chunks
// of 512 rows (16 steps), 1024 blocks = 4/CU. colk partials (vd0==0).
// ---------------------------------------------------------------------------
__global__ __launch_bounds__(256) void k3_grad(
    const unsigned short* __restrict__ diff16,
    const unsigned short* __restrict__ k16,
    float* __restrict__ grad, float* __restrict__ colk_part)
{
  __shared__ __align__(16) unsigned short At[2][128][40];
  __shared__ __align__(16) unsigned short Bt[2][128][40];
  const int t = threadIdx.x, lane = t & 63, wv = t >> 6;
  const int b = blockIdx.x;
  const int x = b & 7;
  const int q = b >> 3;
  const int tile = q & 15;
  const int kc = ((q >> 4) << 3) | x;       // 0..63; chunk tiles share an XCD
  const int vd0 = (tile & 3) << 7;
  const int kd0 = (tile >> 2) << 7;
  const size_t r0 = (size_t)kc << 9;        // 512 rows, 16 steps of 32

  f32x4 acc[4][4];
#pragma unroll
  for (int m = 0; m < 4; ++m)
#pragma unroll
    for (int n = 0; n < 4; ++n)
      acc[m][n] = (f32x4){0.f, 0.f, 0.f, 0.f};

  float ck[16];
#pragma unroll
  for (int j = 0; j < 16; ++j) ck[j] = 0.f;

  const int dr = t >> 3;
  const int c0 = (t & 7) << 4;
  const int wr = (wv >> 1) << 6, wc = (wv & 1) << 6;
  const int fr = lane & 15, fq = lane >> 4;
  const int swz = ((c0 >> 4) & 3) << 3;
  const int drs = dr ^ swz;

#define K3_LOAD(s, A0, A1, B0, B1) do {                                     \
    const size_t ro_ = (r0 + ((size_t)(s) << 5) + dr) << 9;                 \
    A0 = *reinterpret_cast<const ushort8_t*>(&diff16[ro_ + vd0 + c0]);      \
    A1 = *reinterpret_cast<const ushort8_t*>(&diff16[ro_ + vd0 + c0 + 8]);  \
    B0 = *reinterpret_cast<const ushort8_t*>(&k16[ro_ + kd0 + c0]);         \
    B1 = *reinterpret_cast<const ushort8_t*>(&k16[ro_ + kd0 + c0 + 8]);     \
  } while (0)

#define K3_WRITE(buf, A0, A1, B0, B1) do {                                  \
    _Pragma("unroll")                                                       \
    for (int j = 0; j < 8; ++j) {                                           \
      At[buf][c0 + j][drs] = A0[j];                                         \
      At[buf][c0 + 8 + j][drs] = A1[j];                                     \
      Bt[buf][c0 + j][drs] = B0[j];                                         \
      Bt[buf][c0 + 8 + j][drs] = B1[j];                                     \
    }                                                                       \
    if (vd0 == 0) {                                                         \
      _Pragma("unroll")                                                     \
      for (int j = 0; j < 8; ++j) {                                         \
        ck[j] += bf2f(B0[j]); ck[8 + j] += bf2f(B1[j]);                     \
      }                                                                     \
    } } while (0)

#define K3_MFMA(buf) do {                                                   \
    bf16x8 af[4], bfv[4];                                                   \
    _Pragma("unroll")                                                       \
    for (int m = 0; m < 4; ++m) {                                           \
      const int rA = wr + (m << 4) + fr;                                    \
      af[m] = *reinterpret_cast<const bf16x8*>(                             \
          &At[buf][rA][(fq ^ ((rA >> 4) & 3)) << 3]);                       \
    }                                                                       \
    _Pragma("unroll")                                                       \
    for (int n = 0; n < 4; ++n) {                                           \
      const int rB = wc + (n << 4) + fr;                                    \
      bfv[n] = *reinterpret_cast<const bf16x8*>(                            \
          &Bt[buf][rB][(fq ^ ((rB >> 4) & 3)) << 3]);                       \
    }                                                                       \
    _Pragma("unroll")                                                       \
    for (int m = 0; m < 4; ++m)                                             \
      _Pragma("unroll")                                                     \
      for (int n = 0; n < 4; ++n)                                           \
        acc[m][n] = __builtin_amdgcn_mfma_f32_16x16x32_bf16(                \
            af[m], bfv[n], acc[m][n], 0, 0, 0);                             \
  } while (0)

#define K3_LBAR() do {                                                      \
    asm volatile("s_waitcnt lgkmcnt(0)" ::: "memory");                      \
    __builtin_amdgcn_s_barrier();                                           \
  } while (0)

  ushort8_t a0A, a1A, b0A, b1A, a0B, a1B, b0B, b1B;
  K3_LOAD(0, a0A, a1A, b0A, b1A);
  K3_WRITE(0, a0A, a1A, b0A, b1A);
  K3_LOAD(1, a0B, a1B, b0B, b1B);
  K3_LBAR();

  // steady state: 7 double-steps cover s = 0..13 (16 steps total)
#pragma unroll 1
  for (int it = 0; it < 7; ++it) {
    const int s = it << 1;
    K3_LOAD(s + 2, a0A, a1A, b0A, b1A);
    K3_WRITE(1, a0B, a1B, b0B, b1B);
    K3_MFMA(0);
    K3_LBAR();
    K3_LOAD(s + 3, a0B, a1B, b0B, b1B);
    K3_WRITE(0, a0A, a1A, b0A, b1A);
    K3_MFMA(1);
    K3_LBAR();
  }
  // epilogue: s=14: write data(15)->buf1; MFMA buf0; s=15: MFMA buf1
  K3_WRITE(1, a0B, a1B, b0B, b1B);
  K3_MFMA(0);
  K3_LBAR();
  K3_MFMA(1);

#undef K3_LOAD
#undef K3_WRITE
#undef K3_MFMA
#undef K3_LBAR

#pragma unroll
  for (int m = 0; m < 4; ++m)
#pragma unroll
    for (int n = 0; n < 4; ++n)
#pragma unroll
      for (int i = 0; i < 4; ++i)
        atomicAdd(&grad[(size_t)(vd0 + wr + (m << 4) + (fq << 2) + i) * 512
                        + kd0 + wc + (n << 4) + fr], acc[m][n][i]);

  if (vd0 == 0) {
#pragma unroll
    for (int j = 0; j < 16; ++j) {
      ck[j] += __shfl_xor(ck[j], 8);
      ck[j] += __shfl_xor(ck[j], 16);
      ck[j] += __shfl_xor(ck[j], 32);
    }
    __syncthreads();
    float* cred = (float*)&At[0][0][0];
    if (lane < 8) {
#pragma unroll
      for (int j = 0; j < 16; ++j) cred[(wv << 7) + (lane << 4) + j] = ck[j];
    }
    __syncthreads();
    if (t < 128) {
      colk_part[(size_t)kc * 512 + kd0 + t] =
          cred[t] + cred[128 + t] + cred[256 + t] + cred[384 + t];
    }
  }
}

// ---------------------------------------------------------------------------
// cR: blocks 0..31 reduce colk (P=64) / colv (P=256) partials;
// blocks 32..47: 6 dot products {SS,Sg,gg,WW,WS,Wg} -> scal[8..13] atomics.
// ---------------------------------------------------------------------------
__global__ __launch_bounds__(256) void cR_reduce(
    const float* __restrict__ ckp, const float* __restrict__ cvp,
    float* __restrict__ colk, float* __restrict__ colv,
    const float* __restrict__ grad, const float* __restrict__ S,
    const float* __restrict__ Wm, float* __restrict__ scal)
{
  const int t = threadIdx.x, b = blockIdx.x;
  if (b < 32) {
    __shared__ float red[8][32];
    const int mtx = b >> 4;
    const int c = ((b & 15) << 5) + (t & 31);
    const int pg = t >> 5;
    const float* src = mtx ? cvp : ckp;
    const int P = mtx ? 256 : 64;
    float s = 0.f;
    for (int p = pg; p < P; p += 8) s += src[(size_t)p * 512 + c];
    red[pg][t & 31] = s;
    __syncthreads();
    if (pg == 0) {
      float tot = 0.f;
#pragma unroll
      for (int j = 0; j < 8; ++j) tot += red[j][t & 31];
      (mtx ? colv : colk)[c] = tot;
    }
  } else {
    __shared__ float red6[6][4];
    const int qb = b - 32;
    float d[6] = {0.f, 0.f, 0.f, 0.f, 0.f, 0.f};
#pragma unroll
    for (int j = 0; j < 16; ++j) {
      const int i = (qb << 14) + (j << 10) + (t << 2);
      const float4_t g4 = *reinterpret_cast<const float4_t*>(&grad[i]);
      const float4_t s4 = *reinterpret_cast<const float4_t*>(&S[i]);
      const float4_t w4 = *reinterpret_cast<const float4_t*>(&Wm[i]);
#pragma unroll
      for (int e = 0; e < 4; ++e) {
        float gt = g4[e] * (2.0f / 16777216.0f);
        gt = fminf(1.0f, fmaxf(-1.0f, gt));
        d[0] += s4[e] * s4[e];
        d[1] += s4[e] * gt;
        d[2] += gt * gt;
        d[3] += w4[e] * w4[e];
        d[4] += w4[e] * s4[e];
        d[5] += w4[e] * gt;
      }
    }
    const int lane = t & 63, wvi = t >> 6;
#pragma unroll
    for (int k = 0; k < 6; ++k) {
#pragma unroll
      for (int o = 32; o; o >>= 1) d[k] += __shfl_xor(d[k], o);
    }
    if (lane == 0) {
#pragma unroll
      for (int k = 0; k < 6; ++k) red6[k][wvi] = d[k];
    }
    __syncthreads();
    if (t < 6)
      atomicAdd(&scal[8 + t], red6[t][0] + red6[t][1] + red6[t][2] + red6[t][3]);
  }
}

// ---------------------------------------------------------------------------
// c1b: gates + loss + closed-form norm scalars (sm, sw).
// ---------------------------------------------------------------------------
__global__ __launch_bounds__(256) void c1b_gates(
    const float* __restrict__ gw, const float* __restrict__ gb,
    const float* __restrict__ colk, const float* __restrict__ colv,
    const float* __restrict__ lossp, float* __restrict__ scal,
    float* __restrict__ outp)
{
  __shared__ float red3[3][4];
  __shared__ float redl[4];
  const int t = threadIdx.x, lane = t & 63, wvi = t >> 6;
  float p3[3] = {0.f, 0.f, 0.f};
  for (int j = t; j < 1024; j += 256) {
    const float kv = (j < 512 ? colk[j] : colv[j - 512]) * (1.0f / 32768.0f);
    p3[0] += kv * gw[j];
    p3[1] += kv * gw[1024 + j];
    p3[2] += kv * gw[2048 + j];
  }
  float ls = lossp[t] + lossp[256 + t] + lossp[512 + t] + lossp[768 + t];
#pragma unroll
  for (int o = 32; o; o >>= 1) {
    ls += __shfl_xor(ls, o);
#pragma unroll
    for (int g = 0; g < 3; ++g) p3[g] += __shfl_xor(p3[g], o);
  }
  if (lane == 0) {
    red3[0][wvi] = p3[0]; red3[1][wvi] = p3[1]; red3[2][wvi] = p3[2];
    redl[wvi] = ls;
  }
  __syncthreads();
  if (t == 0) {
    const float s0 = red3[0][0] + red3[0][1] + red3[0][2] + red3[0][3] + gb[0];
    const float s1 = red3[1][0] + red3[1][1] + red3[1][2] + red3[1][3] + gb[1];
    const float s2 = red3[2][0] + red3[2][1] + red3[2][2] + red3[2][3] + gb[2];
    const float alpha = 1.0f / (1.0f + expf(-s0));
    const float eta   = 1.0f / (1.0f + expf(-s1));
    const float theta = 1.0f / (1.0f + expf(-s2));
    const float ct = 0.005f * theta;
    const float SS = scal[8], Sg = scal[9], gg = scal[10];
    const float WW = scal[11], WS = scal[12], Wg = scal[13];
    const float nm2 = eta * eta * SS - 2.0f * eta * ct * Sg + ct * ct * gg;
    const float nm = sqrtf(fmaxf(nm2, 0.f));
    const float sm = nm > 5.0f ? 5.0f / (nm + 1e-8f) : 1.0f;
    const float Wmred = sm * (eta * WS - ct * Wg);
    const float oma = 1.0f - alpha;
    const float nw2 = oma * oma * WW + 2.0f * oma * Wmred + sm * sm * nm2;
    const float nw = sqrtf(fmaxf(nw2, 0.f));
    const float sw = nw > 5.0f ? 5.0f / (nw + 1e-8f) : 1.0f;
    scal[3] = alpha; scal[4] = eta; scal[5] = theta;
    scal[6] = sm; scal[7] = sw;
    outp[OUT_LOSS] = (redl[0] + redl[1] + redl[2] + redl[3]) * (1.0f / 16777216.0f);
    outp[OUT_ALPHA]     = alpha;
    outp[OUT_ALPHA + 1] = eta;
    outp[OUT_ALPHA + 2] = theta;
  }
}

// ---------------------------------------------------------------------------
// cF: single pass -> new_momentum, new_weight.
// ---------------------------------------------------------------------------
__global__ __launch_bounds__(256) void cF_final(
    const float* __restrict__ grad, const float* __restrict__ S,
    const float* __restrict__ Wm, const float* __restrict__ scal,
    float* __restrict__ outp)
{
  const float alpha = scal[3], eta = scal[4];
  const float ct = 0.005f * scal[5];
  const float sm = scal[6], sw = scal[7];
  const float oma = 1.0f - alpha;
  const int i = ((blockIdx.x << 8) + threadIdx.x) << 2;
  const float4_t g4 = *reinterpret_cast<const float4_t*>(&grad[i]);
  const float4_t s4 = *reinterpret_cast<const float4_t*>(&S[i]);
  const float4_t w4 = *reinterpret_cast<const float4_t*>(&Wm[i]);
#pragma unroll
  for (int j = 0; j < 4; ++j) {
    float gt = g4[j] * (2.0f / 16777216.0f);
    gt = fminf(1.0f, fmaxf(-1.0f, gt));
    const float m = sm * (eta * s4[j] - ct * gt);
    outp[OUT_MOM + i + j] = m;
    outp[OUT_W + i + j] = sw * (oma * w4[j] + m);
  }
}

// ---------------------------------------------------------------------------
extern "C" void kernel_launch(void* const* d_in, const int* in_sizes, int n_in,
                              void* d_out, int out_size, void* d_ws, size_t ws_size,
                              hipStream_t stream)
{
  const float* Kp = (const float*)d_in[0];
  const float* Vp = (const float*)d_in[1];
  const float* Wp = (const float*)d_in[2];
  const float* GW = (const float*)d_in[3];
  const float* GB = (const float*)d_in[4];
  const float* Sp = (const float*)d_in[5];
  float* outp = (float*)d_out;
  char* ws = (char*)d_ws;

  float* grad            = (float*)(ws + OFF_GRAD);
  float* colk_part       = (float*)(ws + OFF_CKP);
  float* colv_part       = (float*)(ws + OFF_CVP);
  float* loss_part       = (float*)(ws + OFF_LOSSP);
  float* colk            = (float*)(ws + OFF_COLK);
  float* colv            = (float*)(ws + OFF_COLV);
  float* scal            = (float*)(ws + OFF_SCAL);
  unsigned short* w16    = (unsigned short*)(ws + OFF_W16);
  unsigned short* k16    = (unsigned short*)(ws + OFF_K16);
  unsigned short* diff16 = (unsigned short*)(ws + OFF_DIFF);

  k1_convert<<<1056, 256, 0, stream>>>(Kp, Wp, k16, w16, grad, scal);
  k2_gemm<<<1024, 256, 0, stream>>>(k16, w16, Vp, outp, diff16, colv_part, loss_part);
  k3_grad<<<1024, 256, 0, stream>>>(diff16, k16, grad, colk_part);
  cR_reduce<<<48, 256, 0, stream>>>(colk_part, colv_part, colk, colv,
                                    grad, Sp, Wp, scal);
  c1b_gates<<<1, 256, 0, stream>>>(GW, GB, colk, colv, loss_part, scal, outp);
  cF_final<<<256, 256, 0, stream>>>(grad, Sp, Wp, scal, outp);
}

// Round 13
// 146.807 us; speedup vs baseline: 1.1301x; 1.1301x over previous
//
#include <hip/hip_runtime.h>
#include <math.h>

// ---------------------------------------------------------------------------
// TitansMemoryModule fused update, MI355X (gfx950) — round 13
// (= round 10 verbatim, the session's best verified config: 153.1 us)
//   K1: pure f32->bf16 convert of K,W (1040 blocks) + grad/scal zero
//   K2: proven drain-barrier GEMM (77us): 128x128, BK=64, single-buffer,
//       global_load_lds(16B), linear LDS, XCD-grouped, fused epilogue
//   K3: grad = diff^T @ k, split-K 32 chunks, lgkmcnt-only barrier pipeline,
//       2-deep named-reg prefetch, dbuf LDS, fused colk partials
//   cR: colk/colv partial reduction + 6 dot products (SS,Sg,gg,WW,WS,Wg)
//   c1b: gates + loss + closed-form norm scalars; cF: single final pass
// Output (flat f32): retrieved[16777216], loss, new_weight[262144],
//   new_momentum[262144], alpha, eta, theta
// ---------------------------------------------------------------------------

typedef __bf16 bf16x8 __attribute__((ext_vector_type(8)));
typedef float f32x4 __attribute__((ext_vector_type(4)));
typedef float float4_t __attribute__((ext_vector_type(4)));
typedef unsigned short ushort4_t __attribute__((ext_vector_type(4)));
typedef unsigned short ushort8_t __attribute__((ext_vector_type(8)));

#define OUT_LOSS   16777216
#define OUT_W      16777217
#define OUT_MOM    17039361
#define OUT_ALPHA  17301505

// ws layout (bytes)
#define OFF_GRAD   0u           // grad accum [512][512] f32 = 1 MB [K1 zeroes]
#define OFF_CKP    1048576u     // colk_part [32][512] f32 (K3)
#define OFF_CVP    1572864u     // colv_part [256][512] f32 (K2)
#define OFF_LOSSP  2097152u     // loss_part [1024] f32 (K2)
#define OFF_COLK   2105344u     // colk [512] f32
#define OFF_COLV   2107392u     // colv [512] f32
#define OFF_SCAL   2109440u     // scal[16]: 3=a 4=e 5=t 6=sm 7=sw 8..13=dots
#define OFF_W16    2109504u     // 512 KB bf16 W
#define OFF_K16    2633792u     // 32 MB bf16 K (row-major)
#define OFF_DIFF   36188224u    // 32 MB bf16 diff (row-major)

__device__ __forceinline__ ushort4_t cvt4(float4_t v) {
  union { __bf16 b; unsigned short u; } c0, c1, c2, c3;
  c0.b = (__bf16)v.x; c1.b = (__bf16)v.y; c2.b = (__bf16)v.z; c3.b = (__bf16)v.w;
  ushort4_t h; h.x = c0.u; h.y = c1.u; h.z = c2.u; h.w = c3.u;
  return h;
}

__device__ __forceinline__ float bf2f(unsigned short u) {
  return __uint_as_float(((unsigned int)u) << 16);
}

__device__ __forceinline__ void gload_lds16(const unsigned short* g, unsigned short* l) {
  __builtin_amdgcn_global_load_lds(
      (const __attribute__((address_space(1))) unsigned int*)g,
      (__attribute__((address_space(3))) unsigned int*)l, 16, 0, 0);
}

// ---------------------------------------------------------------------------
// K1: pure convert, high MLP. Blocks 0..1023: K; 1024..1039: W;
// 1040..1055: zero grad (+ scal on block 1040).
// ---------------------------------------------------------------------------
__global__ __launch_bounds__(256) void k1_convert(
    const float* __restrict__ Kp, const float* __restrict__ Wp,
    unsigned short* __restrict__ k16, unsigned short* __restrict__ w16,
    float* __restrict__ grad, float* __restrict__ scal)
{
  const int b = blockIdx.x;
  const int t = threadIdx.x;
  if (b < 1040) {
    const float* src = (b < 1024) ? Kp : Wp;
    unsigned short* dst = (b < 1024) ? k16 : w16;
    const size_t base = (size_t)(b < 1024 ? b : b - 1024) * 16384;
#pragma unroll
    for (int j = 0; j < 8; ++j) {
      const size_t off = base + (size_t)j * 2048 + ((size_t)t << 3);
      const float4_t v0 = *reinterpret_cast<const float4_t*>(&src[off]);
      const float4_t v1 = *reinterpret_cast<const float4_t*>(&src[off + 4]);
      const ushort4_t h0 = cvt4(v0), h1 = cvt4(v1);
      ushort8_t h;
      h[0] = h0.x; h[1] = h0.y; h[2] = h0.z; h[3] = h0.w;
      h[4] = h1.x; h[5] = h1.y; h[6] = h1.z; h[7] = h1.w;
      *reinterpret_cast<ushort8_t*>(&dst[off]) = h;
    }
  } else {
    const int base = (b - 1040) << 14;
    const float4_t z = (float4_t){0.f, 0.f, 0.f, 0.f};
#pragma unroll
    for (int j = 0; j < 16; ++j)
      *reinterpret_cast<float4_t*>(&grad[base + (j << 10) + (t << 2)]) = z;
    if (b == 1040 && t < 16) scal[t] = 0.f;
  }
}

// ---------------------------------------------------------------------------
// K2: retrieved = k16 @ w16^T.  Proven structure (77us): 128x128 tile,
// BK=64, 4 waves, single-buffer, global_load_lds(16B), linear LDS,
// XCD-grouped swizzle, fused epilogue.
// ---------------------------------------------------------------------------
__global__ __launch_bounds__(256) void k2_gemm(
    const unsigned short* __restrict__ k16, const unsigned short* __restrict__ w16,
    const float* __restrict__ Vp, float* __restrict__ outp,
    unsigned short* __restrict__ diff16,
    float* __restrict__ colv_part, float* __restrict__ loss_part)
{
  __shared__ __align__(16) unsigned short As[8192];
  __shared__ __align__(16) unsigned short Bs[8192];
  __shared__ float redc[256];
  __shared__ float redl[4];

  const int t = threadIdx.x, lane = t & 63, wv = t >> 6;
  const int tile = (blockIdx.x & 7) * 128 + (blockIdx.x >> 3);
  const int rt = tile >> 2, vt = tile & 3;
  const int row0 = rt << 7, vd0 = vt << 7;

  f32x4 acc[4][4];
#pragma unroll
  for (int m = 0; m < 4; ++m)
#pragma unroll
    for (int n = 0; n < 4; ++n)
      acc[m][n] = (f32x4){0.f, 0.f, 0.f, 0.f};

  const int srow = (wv << 3) + (lane >> 3);
  const int scol = (lane & 7) << 3;
  const unsigned short* pA = k16 + (size_t)(row0 + srow) * 512 + scol;
  const unsigned short* pB = w16 + (size_t)(vd0 + srow) * 512 + scol;
  unsigned short* lA = &As[wv << 9];
  unsigned short* lB = &Bs[wv << 9];

  const int fr = lane & 15, fq = lane >> 4;
  const int wr = (wv >> 1) << 6, wc = (wv & 1) << 6;

  for (int kk0 = 0; kk0 < 512; kk0 += 64) {
#pragma unroll
    for (int i = 0; i < 4; ++i) {
      gload_lds16(pA + (i << 14) + kk0, lA + (i << 11));
      gload_lds16(pB + (i << 14) + kk0, lB + (i << 11));
    }
    __syncthreads();
#pragma unroll
    for (int kk = 0; kk < 64; kk += 32) {
      const int co = kk + (fq << 3);
      bf16x8 af[4], bfv[4];
#pragma unroll
      for (int m = 0; m < 4; ++m)
        af[m] = *reinterpret_cast<const bf16x8*>(&As[((wr + (m << 4) + fr) << 6) + co]);
#pragma unroll
      for (int n = 0; n < 4; ++n)
        bfv[n] = *reinterpret_cast<const bf16x8*>(&Bs[((wc + (n << 4) + fr) << 6) + co]);
#pragma unroll
      for (int m = 0; m < 4; ++m)
#pragma unroll
        for (int n = 0; n < 4; ++n)
          acc[m][n] = __builtin_amdgcn_mfma_f32_16x16x32_bf16(af[m], bfv[n], acc[m][n], 0, 0, 0);
    }
    __syncthreads();
  }

  float lsum = 0.f;
  float vcs[4] = {0.f, 0.f, 0.f, 0.f};
#pragma unroll
  for (int m = 0; m < 4; ++m) {
#pragma unroll
    for (int n = 0; n < 4; ++n) {
#pragma unroll
      for (int i = 0; i < 4; ++i) {
        const int gr = row0 + wr + (m << 4) + (fq << 2) + i;
        const int gc = vd0 + wc + (n << 4) + fr;
        const size_t oi = (size_t)gr * 512 + gc;
        const float rv = acc[m][n][i];
        outp[oi] = rv;
        const float vv = Vp[oi];
        const float d = rv - vv;
        lsum += d * d;
        vcs[n] += vv;
        union { __bf16 b; unsigned short u; } cd; cd.b = (__bf16)d;
        diff16[oi] = cd.u;
      }
    }
  }
#pragma unroll
  for (int o = 32; o; o >>= 1) lsum += __shfl_xor(lsum, o);
  if (lane == 0) redl[wv] = lsum;
#pragma unroll
  for (int n = 0; n < 4; ++n) {
    vcs[n] += __shfl_xor(vcs[n], 16);
    vcs[n] += __shfl_xor(vcs[n], 32);
  }
  if (fq == 0) {
#pragma unroll
    for (int n = 0; n < 4; ++n)
      redc[(wv << 6) + (n << 4) + fr] = vcs[n];
  }
  __syncthreads();
  if (t < 128) {
    const int side = t >> 6, lc = t & 63;
    colv_part[(size_t)rt * 512 + vd0 + t] =
        redc[side * 64 + lc] + redc[(side + 2) * 64 + lc];
  }
  if (t == 0)
    loss_part[tile] = redl[0] + redl[1] + redl[2] + redl[3];
}

// ---------------------------------------------------------------------------
// K3: grad += diff^T @ k. lgkmcnt-only barrier pipeline (r9/r10 proven),
// split-K 32 chunks of 1024 rows, 512 blocks, XCD-grouped; colk fused.
// ---------------------------------------------------------------------------
__global__ __launch_bounds__(256) void k3_grad(
    const unsigned short* __restrict__ diff16,
    const unsigned short* __restrict__ k16,
    float* __restrict__ grad, float* __restrict__ colk_part)
{
  __shared__ __align__(16) unsigned short At[2][128][40];
  __shared__ __align__(16) unsigned short Bt[2][128][40];
  const int t = threadIdx.x, lane = t & 63, wv = t >> 6;
  const int b = blockIdx.x;
  const int x = b & 7;
  const int q = b >> 3;
  const int tile = q & 15;
  const int kc = ((q >> 4) << 3) | x;
  const int vd0 = (tile & 3) << 7;
  const int kd0 = (tile >> 2) << 7;
  const size_t r0 = (size_t)kc << 10;

  f32x4 acc[4][4];
#pragma unroll
  for (int m = 0; m < 4; ++m)
#pragma unroll
    for (int n = 0; n < 4; ++n)
      acc[m][n] = (f32x4){0.f, 0.f, 0.f, 0.f};

  float ck[16];
#pragma unroll
  for (int j = 0; j < 16; ++j) ck[j] = 0.f;

  const int dr = t >> 3;
  const int c0 = (t & 7) << 4;
  const int wr = (wv >> 1) << 6, wc = (wv & 1) << 6;
  const int fr = lane & 15, fq = lane >> 4;
  const int swz = ((c0 >> 4) & 3) << 3;
  const int drs = dr ^ swz;

#define K3_LOAD(s, A0, A1, B0, B1) do {                                     \
    const size_t ro_ = (r0 + ((size_t)(s) << 5) + dr) << 9;                 \
    A0 = *reinterpret_cast<const ushort8_t*>(&diff16[ro_ + vd0 + c0]);      \
    A1 = *reinterpret_cast<const ushort8_t*>(&diff16[ro_ + vd0 + c0 + 8]);  \
    B0 = *reinterpret_cast<const ushort8_t*>(&k16[ro_ + kd0 + c0]);         \
    B1 = *reinterpret_cast<const ushort8_t*>(&k16[ro_ + kd0 + c0 + 8]);     \
  } while (0)

#define K3_WRITE(buf, A0, A1, B0, B1) do {                                  \
    _Pragma("unroll")                                                       \
    for (int j = 0; j < 8; ++j) {                                           \
      At[buf][c0 + j][drs] = A0[j];                                         \
      At[buf][c0 + 8 + j][drs] = A1[j];                                     \
      Bt[buf][c0 + j][drs] = B0[j];                                         \
      Bt[buf][c0 + 8 + j][drs] = B1[j];                                     \
    }                                                                       \
    if (vd0 == 0) {                                                         \
      _Pragma("unroll")                                                     \
      for (int j = 0; j < 8; ++j) {                                         \
        ck[j] += bf2f(B0[j]); ck[8 + j] += bf2f(B1[j]);                     \
      }                                                                     \
    } } while (0)

#define K3_MFMA(buf) do {                                                   \
    bf16x8 af[4], bfv[4];                                                   \
    _Pragma("unroll")                                                       \
    for (int m = 0; m < 4; ++m) {                                           \
      const int rA = wr + (m << 4) + fr;                                    \
      af[m] = *reinterpret_cast<const bf16x8*>(                             \
          &At[buf][rA][(fq ^ ((rA >> 4) & 3)) << 3]);                       \
    }                                                                       \
    _Pragma("unroll")                                                       \
    for (int n = 0; n < 4; ++n) {                                           \
      const int rB = wc + (n << 4) + fr;                                    \
      bfv[n] = *reinterpret_cast<const bf16x8*>(                            \
          &Bt[buf][rB][(fq ^ ((rB >> 4) & 3)) << 3]);                       \
    }                                                                       \
    _Pragma("unroll")                                                       \
    for (int m = 0; m < 4; ++m)                                             \
      _Pragma("unroll")                                                     \
      for (int n = 0; n < 4; ++n)                                           \
        acc[m][n] = __builtin_amdgcn_mfma_f32_16x16x32_bf16(                \
            af[m], bfv[n], acc[m][n], 0, 0, 0);                             \
  } while (0)

#define K3_LBAR() do {                                                      \
    asm volatile("s_waitcnt lgkmcnt(0)" ::: "memory");                      \
    __builtin_amdgcn_s_barrier();                                           \
  } while (0)

  ushort8_t a0A, a1A, b0A, b1A, a0B, a1B, b0B, b1B;
  K3_LOAD(0, a0A, a1A, b0A, b1A);
  K3_WRITE(0, a0A, a1A, b0A, b1A);
  K3_LOAD(1, a0B, a1B, b0B, b1B);
  K3_LBAR();

#pragma unroll 1
  for (int it = 0; it < 15; ++it) {
    const int s = it << 1;
    K3_LOAD(s + 2, a0A, a1A, b0A, b1A);
    K3_WRITE(1, a0B, a1B, b0B, b1B);
    K3_MFMA(0);
    K3_LBAR();
    K3_LOAD(s + 3, a0B, a1B, b0B, b1B);
    K3_WRITE(0, a0A, a1A, b0A, b1A);
    K3_MFMA(1);
    K3_LBAR();
  }
  K3_WRITE(1, a0B, a1B, b0B, b1B);
  K3_MFMA(0);
  K3_LBAR();
  K3_MFMA(1);

#undef K3_LOAD
#undef K3_WRITE
#undef K3_MFMA
#undef K3_LBAR

#pragma unroll
  for (int m = 0; m < 4; ++m)
#pragma unroll
    for (int n = 0; n < 4; ++n)
#pragma unroll
      for (int i = 0; i < 4; ++i)
        atomicAdd(&grad[(size_t)(vd0 + wr + (m << 4) + (fq << 2) + i) * 512
                        + kd0 + wc + (n << 4) + fr], acc[m][n][i]);

  if (vd0 == 0) {
#pragma unroll
    for (int j = 0; j < 16; ++j) {
      ck[j] += __shfl_xor(ck[j], 8);
      ck[j] += __shfl_xor(ck[j], 16);
      ck[j] += __shfl_xor(ck[j], 32);
    }
    __syncthreads();
    float* cred = (float*)&At[0][0][0];
    if (lane < 8) {
#pragma unroll
      for (int j = 0; j < 16; ++j) cred[(wv << 7) + (lane << 4) + j] = ck[j];
    }
    __syncthreads();
    if (t < 128) {
      colk_part[(size_t)kc * 512 + kd0 + t] =
          cred[t] + cred[128 + t] + cred[256 + t] + cred[384 + t];
    }
  }
}

// ---------------------------------------------------------------------------
// cR: blocks 0..31 reduce colk (P=32) / colv (P=256) partials;
// blocks 32..47: 6 dot products {SS,Sg,gg,WW,WS,Wg} -> scal[8..13] atomics.
// ---------------------------------------------------------------------------
__global__ __launch_bounds__(256) void cR_reduce(
    const float* __restrict__ ckp, const float* __restrict__ cvp,
    float* __restrict__ colk, float* __restrict__ colv,
    const float* __restrict__ grad, const float* __restrict__ S,
    const float* __restrict__ Wm, float* __restrict__ scal)
{
  const int t = threadIdx.x, b = blockIdx.x;
  if (b < 32) {
    __shared__ float red[8][32];
    const int mtx = b >> 4;
    const int c = ((b & 15) << 5) + (t & 31);
    const int pg = t >> 5;
    const float* src = mtx ? cvp : ckp;
    const int P = mtx ? 256 : 32;
    float s = 0.f;
    for (int p = pg; p < P; p += 8) s += src[(size_t)p * 512 + c];
    red[pg][t & 31] = s;
    __syncthreads();
    if (pg == 0) {
      float tot = 0.f;
#pragma unroll
      for (int j = 0; j < 8; ++j) tot += red[j][t & 31];
      (mtx ? colv : colk)[c] = tot;
    }
  } else {
    __shared__ float red6[6][4];
    const int qb = b - 32;
    float d[6] = {0.f, 0.f, 0.f, 0.f, 0.f, 0.f};
#pragma unroll
    for (int j = 0; j < 16; ++j) {
      const int i = (qb << 14) + (j << 10) + (t << 2);
      const float4_t g4 = *reinterpret_cast<const float4_t*>(&grad[i]);
      const float4_t s4 = *reinterpret_cast<const float4_t*>(&S[i]);
      const float4_t w4 = *reinterpret_cast<const float4_t*>(&Wm[i]);
#pragma unroll
      for (int e = 0; e < 4; ++e) {
        float gt = g4[e] * (2.0f / 16777216.0f);
        gt = fminf(1.0f, fmaxf(-1.0f, gt));
        d[0] += s4[e] * s4[e];
        d[1] += s4[e] * gt;
        d[2] += gt * gt;
        d[3] += w4[e] * w4[e];
        d[4] += w4[e] * s4[e];
        d[5] += w4[e] * gt;
      }
    }
    const int lane = t & 63, wvi = t >> 6;
#pragma unroll
    for (int k = 0; k < 6; ++k) {
#pragma unroll
      for (int o = 32; o; o >>= 1) d[k] += __shfl_xor(d[k], o);
    }
    if (lane == 0) {
#pragma unroll
      for (int k = 0; k < 6; ++k) red6[k][wvi] = d[k];
    }
    __syncthreads();
    if (t < 6)
      atomicAdd(&scal[8 + t], red6[t][0] + red6[t][1] + red6[t][2] + red6[t][3]);
  }
}

// ---------------------------------------------------------------------------
// c1b: gates + loss + closed-form norm scalars (sm, sw).
// ---------------------------------------------------------------------------
__global__ __launch_bounds__(256) void c1b_gates(
    const float* __restrict__ gw, const float* __restrict__ gb,
    const float* __restrict__ colk, const float* __restrict__ colv,
    const float* __restrict__ lossp, float* __restrict__ scal,
    float* __restrict__ outp)
{
  __shared__ float red3[3][4];
  __shared__ float redl[4];
  const int t = threadIdx.x, lane = t & 63, wvi = t >> 6;
  float p3[3] = {0.f, 0.f, 0.f};
  for (int j = t; j < 1024; j += 256) {
    const float kv = (j < 512 ? colk[j] : colv[j - 512]) * (1.0f / 32768.0f);
    p3[0] += kv * gw[j];
    p3[1] += kv * gw[1024 + j];
    p3[2] += kv * gw[2048 + j];
  }
  float ls = lossp[t] + lossp[256 + t] + lossp[512 + t] + lossp[768 + t];
#pragma unroll
  for (int o = 32; o; o >>= 1) {
    ls += __shfl_xor(ls, o);
#pragma unroll
    for (int g = 0; g < 3; ++g) p3[g] += __shfl_xor(p3[g], o);
  }
  if (lane == 0) {
    red3[0][wvi] = p3[0]; red3[1][wvi] = p3[1]; red3[2][wvi] = p3[2];
    redl[wvi] = ls;
  }
  __syncthreads();
  if (t == 0) {
    const float s0 = red3[0][0] + red3[0][1] + red3[0][2] + red3[0][3] + gb[0];
    const float s1 = red3[1][0] + red3[1][1] + red3[1][2] + red3[1][3] + gb[1];
    const float s2 = red3[2][0] + red3[2][1] + red3[2][2] + red3[2][3] + gb[2];
    const float alpha = 1.0f / (1.0f + expf(-s0));
    const float eta   = 1.0f / (1.0f + expf(-s1));
    const float theta = 1.0f / (1.0f + expf(-s2));
    const float ct = 0.005f * theta;
    const float SS = scal[8], Sg = scal[9], gg = scal[10];
    const float WW = scal[11], WS = scal[12], Wg = scal[13];
    const float nm2 = eta * eta * SS - 2.0f * eta * ct * Sg + ct * ct * gg;
    const float nm = sqrtf(fmaxf(nm2, 0.f));
    const float sm = nm > 5.0f ? 5.0f / (nm + 1e-8f) : 1.0f;
    const float Wmred = sm * (eta * WS - ct * Wg);
    const float oma = 1.0f - alpha;
    const float nw2 = oma * oma * WW + 2.0f * oma * Wmred + sm * sm * nm2;
    const float nw = sqrtf(fmaxf(nw2, 0.f));
    const float sw = nw > 5.0f ? 5.0f / (nw + 1e-8f) : 1.0f;
    scal[3] = alpha; scal[4] = eta; scal[5] = theta;
    scal[6] = sm; scal[7] = sw;
    outp[OUT_LOSS] = (redl[0] + redl[1] + redl[2] + redl[3]) * (1.0f / 16777216.0f);
    outp[OUT_ALPHA]     = alpha;
    outp[OUT_ALPHA + 1] = eta;
    outp[OUT_ALPHA + 2] = theta;
  }
}

// ---------------------------------------------------------------------------
// cF: single pass -> new_momentum, new_weight.
// ---------------------------------------------------------------------------
__global__ __launch_bounds__(256) void cF_final(
    const float* __restrict__ grad, const float* __restrict__ S,
    const float* __restrict__ Wm, const float* __restrict__ scal,
    float* __restrict__ outp)
{
  const float alpha = scal[3], eta = scal[4];
  const float ct = 0.005f * scal[5];
  const float sm = scal[6], sw = scal[7];
  const float oma = 1.0f - alpha;
  const int i = ((blockIdx.x << 8) + threadIdx.x) << 2;
  const float4_t g4 = *reinterpret_cast<const float4_t*>(&grad[i]);
  const float4_t s4 = *reinterpret_cast<const float4_t*>(&S[i]);
  const float4_t w4 = *reinterpret_cast<const float4_t*>(&Wm[i]);
#pragma unroll
  for (int j = 0; j < 4; ++j) {
    float gt = g4[j] * (2.0f / 16777216.0f);
    gt = fminf(1.0f, fmaxf(-1.0f, gt));
    const float m = sm * (eta * s4[j] - ct * gt);
    outp[OUT_MOM + i + j] = m;
    outp[OUT_W + i + j] = sw * (oma * w4[j] + m);
  }
}

// ---------------------------------------------------------------------------
extern "C" void kernel_launch(void* const* d_in, const int* in_sizes, int n_in,
                              void* d_out, int out_size, void* d_ws, size_t ws_size,
                              hipStream_t stream)
{
  const float* Kp = (const float*)d_in[0];
  const float* Vp = (const float*)d_in[1];
  const float* Wp = (const float*)d_in[2];
  const float* GW = (const float*)d_in[3];
  const float* GB = (const float*)d_in[4];
  const float* Sp = (const float*)d_in[5];
  float* outp = (float*)d_out;
  char* ws = (char*)d_ws;

  float* grad            = (float*)(ws + OFF_GRAD);
  float* colk_part       = (float*)(ws + OFF_CKP);
  float* colv_part       = (float*)(ws + OFF_CVP);
  float* loss_part       = (float*)(ws + OFF_LOSSP);
  float* colk            = (float*)(ws + OFF_COLK);
  float* colv            = (float*)(ws + OFF_COLV);
  float* scal            = (float*)(ws + OFF_SCAL);
  unsigned short* w16    = (unsigned short*)(ws + OFF_W16);
  unsigned short* k16    = (unsigned short*)(ws + OFF_K16);
  unsigned short* diff16 = (unsigned short*)(ws + OFF_DIFF);

  k1_convert<<<1056, 256, 0, stream>>>(Kp, Wp, k16, w16, grad, scal);
  k2_gemm<<<1024, 256, 0, stream>>>(k16, w16, Vp, outp, diff16, colv_part, loss_part);
  k3_grad<<<512, 256, 0, stream>>>(diff16, k16, grad, colk_part);
  cR_reduce<<<48, 256, 0, stream>>>(colk_part, colv_part, colk, colv,
                                    grad, Sp, Wp, scal);
  c1b_gates<<<1, 256, 0, stream>>>(GW, GB, colk, colv, loss_part, scal, outp);
  cF_final<<<256, 256, 0, stream>>>(grad, Sp, Wp, scal, outp);
}